// Round 10
// baseline (229.314 us; speedup 1.0000x reference)
//
#include <hip/hip_runtime.h>
#include <cstddef>
#include <cstdint>

#define T_SEQ 2048
#define EMB_D 2048
#define HD_D  128

typedef __attribute__((ext_vector_type(8))) short short8;
typedef __attribute__((ext_vector_type(4))) float f32x4;
typedef __attribute__((ext_vector_type(4))) unsigned short ushort4v;
typedef __attribute__((ext_vector_type(8))) unsigned short ushort8v;

union frag_u { short8 s8; unsigned u[4]; };

static __device__ __forceinline__ unsigned short f2bf_rne(float f) {
    union { float f; unsigned u; } v; v.f = f;
    unsigned r = v.u + 0x7fffu + ((v.u >> 16) & 1u);
    return (unsigned short)(r >> 16);
}
static __device__ __forceinline__ unsigned short f2bf_fast(float f) {
    union { float f; unsigned u; } v; v.f = f;
    return (unsigned short)((v.u + 0x8000u) >> 16);
}
static __device__ __forceinline__ float bf2f(unsigned short h) {
    union { unsigned u; float f; } v; v.u = ((unsigned)h) << 16;
    return v.f;
}
// pack two fp32 -> packed bf16 pair (round-half-up) in 3 VALU
static __device__ __forceinline__ unsigned pk2(float a, float b) {
    union { float f; unsigned u; } x, y; x.f = a; y.f = b;
    return __builtin_amdgcn_perm(y.u + 0x8000u, x.u + 0x8000u, 0x07060302);
}
static __device__ __forceinline__ void dma16(const void* g, void* l) {
    __builtin_amdgcn_global_load_lds(
        (const __attribute__((address_space(1))) unsigned int*)g,
        (__attribute__((address_space(3))) unsigned int*)l, 16, 0, 0);
}
#define EXP2F(x) __builtin_amdgcn_exp2f(x)

// ---------------------------------------------------------------------------
// Kernel 0: coalesced transpose + bf16 convert: Wt[w][n][k] = W_w[k][n]
// ---------------------------------------------------------------------------
__global__ __launch_bounds__(256) void prep_weights(
    const float* __restrict__ Wq, const float* __restrict__ Wk,
    const float* __restrict__ Wv, unsigned short* __restrict__ Wt)
{
    __shared__ __attribute__((aligned(16))) unsigned short tw[64 * 132];
    const int w = blockIdx.y;
    const int k0 = blockIdx.x * 64;
    const float* W = (w == 0) ? Wq : (w == 1) ? Wk : Wv;
    const int tid = threadIdx.x;
#pragma unroll
    for (int p = 0; p < 8; p++) {
        const int f = p * 256 + tid;        // float4 index over 64x32
        const int row = f >> 5, c4 = f & 31;
        const float4 v = *(const float4*)&W[(size_t)(k0 + row) * HD_D + c4 * 4];
        ushort4v h = { f2bf_rne(v.x), f2bf_rne(v.y), f2bf_rne(v.z), f2bf_rne(v.w) };
        *(ushort4v*)&tw[row * 132 + c4 * 4] = h;
    }
    __syncthreads();
    const int n = tid >> 1, h = tid & 1;
    unsigned short* dst = Wt + (size_t)w * (HD_D * EMB_D) + (size_t)n * EMB_D + k0 + h * 32;
#pragma unroll
    for (int j = 0; j < 4; j++) {
        ushort8v o;
#pragma unroll
        for (int jj = 0; jj < 8; jj++) o[jj] = tw[(h * 32 + j * 8 + jj) * 132 + n];
        *(ushort8v*)&dst[j * 8] = o;
    }
}

// ---------------------------------------------------------------------------
// Kernel 1: FUSED QKV projection + RoPE (64 rows x 96 cols, DMA dbuf).
//   R10: XCD swizzle — linear block id L maps xcd=L&7, and all 4 column
//   groups of one m0 land on the SAME xcd (R9 put them on 4 different XCDs:
//   FETCH 134 MB). x now fetched from HBM once per m0, 3x from XCD L2.
// ---------------------------------------------------------------------------
__global__ __launch_bounds__(256, 2) void qkv_fused(
    const float* __restrict__ x, const unsigned short* __restrict__ Wt,
    const float* __restrict__ rcos, const float* __restrict__ rsin,
    unsigned short* __restrict__ Qb, unsigned short* __restrict__ Kb,
    unsigned short* __restrict__ Vt)
{
    __shared__ __attribute__((aligned(16))) float xs[2][64 * 64];            // 2 x 16 KB
    __shared__ __attribute__((aligned(16))) unsigned short wsb[2][96 * 64];  // 2 x 12 KB
    const int L = blockIdx.x;
    const int xcd = L & 7, s = L >> 3;
    const int ng = s & 3;                       // column group (same-xcd for fixed m0)
    const int m0 = (xcd * 16 + (s >> 2)) * 64;  // 128 m-tiles spread across XCDs
    const int tid = threadIdx.x;
    const int lane = tid & 63, wave = tid >> 6;
    const int wm = wave >> 1, wn = wave & 1;    // 2x2 wave grid: 32 rows x 48 cols
    const int l15 = lane & 15, lq = lane >> 4;

    // --- x DMA: 1024 granules (64 rows x 16 x 16B), 4 per thread ---
    const float* xSrc[4]; int xOff[4];
#pragma unroll
    for (int p = 0; p < 4; p++) {
        const int g = p * 256 + tid;
        const int row = g >> 4, c = g & 15;
        xSrc[p] = x + (size_t)(m0 + row) * EMB_D + (c ^ (row & 15)) * 4;
        xOff[p] = (p * 256 + wave * 64) * 4;
    }
    // --- W DMA: 768 granules (96 rows x 8 x 16B), 3 per thread ---
    const unsigned short* wSrc[3]; int wOff[3];
#pragma unroll
    for (int p = 0; p < 3; p++) {
        const int g = p * 256 + tid;
        const int row = g >> 3, c = g & 7;
        wSrc[p] = Wt + (size_t)(ng * 96 + row) * EMB_D + (c ^ (row & 7)) * 8;
        wOff[p] = (p * 256 + wave * 64) * 8;
    }

    int offA[2][2][2];
#pragma unroll
    for (int i = 0; i < 2; i++)
#pragma unroll
        for (int ks = 0; ks < 2; ks++) {
            const int row = wm * 32 + i * 16 + l15;
            const int ga = ks * 8 + lq * 2;
            offA[i][ks][0] = row * 64 + ((ga)     ^ (row & 15)) * 4;
            offA[i][ks][1] = row * 64 + ((ga + 1) ^ (row & 15)) * 4;
        }
    int offB[3][2];
#pragma unroll
    for (int j = 0; j < 3; j++)
#pragma unroll
        for (int ks = 0; ks < 2; ks++) {
            const int row = wn * 48 + j * 16 + l15;
            const int gb = ks * 4 + lq;
            offB[j][ks] = row * 64 + (gb ^ (row & 7)) * 8;
        }

    f32x4 acc[2][3];
#pragma unroll
    for (int i = 0; i < 2; i++)
#pragma unroll
        for (int j = 0; j < 3; j++) acc[i][j] = (f32x4){0.f, 0.f, 0.f, 0.f};

#pragma unroll
    for (int p = 0; p < 4; p++) dma16(xSrc[p], &xs[0][xOff[p]]);
#pragma unroll
    for (int p = 0; p < 3; p++) dma16(wSrc[p], &wsb[0][wOff[p]]);

    for (int k0 = 0; k0 < EMB_D; k0 += 64) {
        const int buf = (k0 >> 6) & 1;
        __syncthreads();   // vmcnt(0): drains buf's DMA (issued one compute-phase ago)
        if (k0 + 64 < EMB_D) {
#pragma unroll
            for (int p = 0; p < 4; p++)
                dma16(xSrc[p] + k0 + 64, &xs[buf ^ 1][xOff[p]]);
#pragma unroll
            for (int p = 0; p < 3; p++)
                dma16(wSrc[p] + k0 + 64, &wsb[buf ^ 1][wOff[p]]);
        }

        frag_u A[2][2];
#pragma unroll
        for (int i = 0; i < 2; i++)
#pragma unroll
            for (int ks = 0; ks < 2; ks++) {
                const f32x4 f0 = *(const f32x4*)&xs[buf][offA[i][ks][0]];
                const f32x4 f1 = *(const f32x4*)&xs[buf][offA[i][ks][1]];
                A[i][ks].u[0] = pk2(f0.x, f0.y);
                A[i][ks].u[1] = pk2(f0.z, f0.w);
                A[i][ks].u[2] = pk2(f1.x, f1.y);
                A[i][ks].u[3] = pk2(f1.z, f1.w);
            }
#pragma unroll
        for (int ks = 0; ks < 2; ks++)
#pragma unroll
            for (int j = 0; j < 3; j++) {
                const short8 B = *(const short8*)&wsb[buf][offB[j][ks]];
#pragma unroll
                for (int i = 0; i < 2; i++)
                    acc[i][j] = __builtin_amdgcn_mfma_f32_16x16x32_bf16(
                        A[i][ks].s8, B, acc[i][j], 0, 0, 0);
            }
    }

    const float qscale = 0.08838834764831845f * 1.4426950408889634f; // 1/sqrt(128)*log2(e)
#pragma unroll
    for (int i = 0; i < 2; i++) {
#pragma unroll
        for (int r = 0; r < 4; r++) {
            const int row = m0 + wm * 32 + i * 16 + lq * 4 + r;   // b*T + t
            const int t = row & (T_SEQ - 1);
            const int bb = row >> 11;
#pragma unroll
            for (int j = 0; j < 3; j++) {
                const int col = ng * 96 + wn * 48 + j * 16 + l15;
                const int mat = col >> 7, mcol = col & 127;
                const float v = acc[i][j][r];
                if (mat == 2) {
                    Vt[((size_t)bb * HD_D + mcol) * T_SEQ + t] = f2bf_rne(v);
                } else {
                    const int ip = mcol >> 1;
                    const float c = rcos[t * 64 + ip];
                    const float s2 = rsin[t * 64 + ip];
                    const float pv = __shfl_xor(v, 1);
                    float rv = (mcol & 1) ? (pv * s2 + v * c) : (v * c - pv * s2);
                    if (mat == 0) {
                        rv *= qscale;
                        Qb[(size_t)row * HD_D + mcol] = f2bf_rne(rv);
                    } else {
                        Kb[(size_t)row * HD_D + mcol] = f2bf_rne(rv);
                    }
                }
            }
        }
    }
}

// ---------------------------------------------------------------------------
// Kernel 2: flash attention, causal, STATIC-MAX softmax, SPLIT-K partials.
//   R10: grid 1024 (2 k-groups per q-tile) = 4 blocks/CU = 16 waves/CU to
//   hide the ~500-cyc K->MFMA->exp2->LDS->MFMA chain (was 8 waves/CU).
//   Blocks write UNNORMALIZED partials (static max makes them plain sums):
//   group 0 -> fp32 in d_out, group 1 -> bf16 in ws; l's in ws. attn_merge
//   combines. L%8 <-> (b,g): one batch's K/V (4 MB) per XCD L2.
// ---------------------------------------------------------------------------
__global__ __launch_bounds__(256, 4) void attn(
    const unsigned short* __restrict__ Qb, const unsigned short* __restrict__ Kb,
    const unsigned short* __restrict__ Vt, float* __restrict__ O0,
    unsigned short* __restrict__ O1, float* __restrict__ Lp)
{
    __shared__ __attribute__((aligned(16))) unsigned short O_s[4][16 * 128];   // 16 KB bf16
    __shared__ __attribute__((aligned(16))) unsigned short P_s[4][2][16 * 40]; // 10 KB
    __shared__ float l_s[4][16];

    const int tid = threadIdx.x;
    const int lane = tid & 63, wave = tid >> 6;
    const int l15 = lane & 15, lq = lane >> 4;
    const int kf = lq * 8;

    const int L = blockIdx.x;
    const int g = L & 1;                         // k-group
    const int b = (L >> 1) & 3;
    const int q0 = (127 - (L >> 3)) * 16;        // heavy q-tiles first
    const int kend = q0 + 16;
    const float M2 = 16.0f;                      // static max (exp2 domain)

    const unsigned short* Qp = Qb + (size_t)(b * T_SEQ + q0) * HD_D;
    short8 aQ[4];
#pragma unroll
    for (int d = 0; d < 4; d++)
        aQ[d] = *(const short8*)&Qp[l15 * HD_D + d * 32 + kf];

    f32x4 acc[8];
#pragma unroll
    for (int d = 0; d < 8; d++) acc[d] = (f32x4){0.f, 0.f, 0.f, 0.f};
    float l_r[4] = {0.f, 0.f, 0.f, 0.f};

    const unsigned short* Kbase = Kb + (size_t)b * T_SEQ * HD_D;
    const unsigned short* Vbase = Vt + (size_t)b * HD_D * T_SEQ;
    unsigned short* PwA = &P_s[wave][0][0];
    unsigned short* PwB = &P_s[wave][1][0];

    // chunk residues: A covers c%16 in {0..7}, B covers {8..15} (over wave,g)
    for (int c = 2 * wave + g; c * 32 < kend; c += 16) {
        const int kA = c * 32;
        const int kB = (c + 8) * 32;
        const bool hB = kB < kend;

        const unsigned short* KpA = Kbase + (size_t)kA * HD_D;
        const unsigned short* KpB = Kbase + (size_t)kB * HD_D;
        short8 KA[8], KB_[8];
#pragma unroll
        for (int d = 0; d < 4; d++)
#pragma unroll
            for (int n = 0; n < 2; n++)
                KA[d * 2 + n] = *(const short8*)&KpA[(size_t)(n * 16 + l15) * HD_D + d * 32 + kf];
        if (hB) {
#pragma unroll
            for (int d = 0; d < 4; d++)
#pragma unroll
                for (int n = 0; n < 2; n++)
                    KB_[d * 2 + n] = *(const short8*)&KpB[(size_t)(n * 16 + l15) * HD_D + d * 32 + kf];
        }

        f32x4 sA0 = (f32x4){0.f, 0.f, 0.f, 0.f}, sA1 = sA0, sB0 = sA0, sB1 = sA0;
#pragma unroll
        for (int d = 0; d < 4; d++) {
            sA0 = __builtin_amdgcn_mfma_f32_16x16x32_bf16(aQ[d], KA[d * 2 + 0], sA0, 0, 0, 0);
            sA1 = __builtin_amdgcn_mfma_f32_16x16x32_bf16(aQ[d], KA[d * 2 + 1], sA1, 0, 0, 0);
        }
        if (hB) {
#pragma unroll
            for (int d = 0; d < 4; d++) {
                sB0 = __builtin_amdgcn_mfma_f32_16x16x32_bf16(aQ[d], KB_[d * 2 + 0], sB0, 0, 0, 0);
                sB1 = __builtin_amdgcn_mfma_f32_16x16x32_bf16(aQ[d], KB_[d * 2 + 1], sB1, 0, 0, 0);
            }
        }

        short8 VA[8];
#pragma unroll
        for (int d = 0; d < 8; d++)
            VA[d] = *(const short8*)&Vbase[(size_t)(d * 16 + l15) * T_SEQ + kA + kf];

#pragma unroll
        for (int r = 0; r < 4; r++) {
            const int q = q0 + lq * 4 + r;
            const float p0 = ((kA + l15)      <= q) ? EXP2F(sA0[r] - M2) : 0.f;
            const float p1 = ((kA + 16 + l15) <= q) ? EXP2F(sA1[r] - M2) : 0.f;
            l_r[r] += p0 + p1;
            const int prow = (lq * 4 + r) * 40;
            PwA[prow + l15]      = f2bf_fast(p0);
            PwA[prow + 16 + l15] = f2bf_fast(p1);
        }
        const short8 pA = *(const short8*)&PwA[l15 * 40 + kf];
#pragma unroll
        for (int d = 0; d < 8; d++)
            acc[d] = __builtin_amdgcn_mfma_f32_16x16x32_bf16(pA, VA[d], acc[d], 0, 0, 0);

        if (hB) {
            short8 VB[8];
#pragma unroll
            for (int d = 0; d < 8; d++)
                VB[d] = *(const short8*)&Vbase[(size_t)(d * 16 + l15) * T_SEQ + kB + kf];
#pragma unroll
            for (int r = 0; r < 4; r++) {
                const int q = q0 + lq * 4 + r;
                const float p0 = ((kB + l15)      <= q) ? EXP2F(sB0[r] - M2) : 0.f;
                const float p1 = ((kB + 16 + l15) <= q) ? EXP2F(sB1[r] - M2) : 0.f;
                l_r[r] += p0 + p1;
                const int prow = (lq * 4 + r) * 40;
                PwB[prow + l15]      = f2bf_fast(p0);
                PwB[prow + 16 + l15] = f2bf_fast(p1);
            }
            const short8 pB = *(const short8*)&PwB[l15 * 40 + kf];
#pragma unroll
            for (int d = 0; d < 8; d++)
                acc[d] = __builtin_amdgcn_mfma_f32_16x16x32_bf16(pB, VB[d], acc[d], 0, 0, 0);
        }
    }

    // ---- in-block 4-way merge (plain sums), then write UNNORMALIZED partial
#pragma unroll
    for (int r = 0; r < 4; r++) {
        float lr = l_r[r];
        lr += __shfl_xor(lr, 1);
        lr += __shfl_xor(lr, 2);
        lr += __shfl_xor(lr, 4);
        lr += __shfl_xor(lr, 8);
        if (l15 == 0) l_s[wave][lq * 4 + r] = lr;
#pragma unroll
        for (int d = 0; d < 8; d++)
            O_s[wave][(lq * 4 + r) * 128 + d * 16 + l15] = f2bf_fast(acc[d][r]);
    }
    __syncthreads();

    const int row = tid >> 4;
    const int dc = (tid & 15) * 8;
    const float lt = l_s[0][row] + l_s[1][row] + l_s[2][row] + l_s[3][row];
    float o[8];
#pragma unroll
    for (int k = 0; k < 8; k++) o[k] = 0.f;
#pragma unroll
    for (int w2 = 0; w2 < 4; w2++) {
        const ushort8v pv = *(const ushort8v*)&O_s[w2][row * 128 + dc];
#pragma unroll
        for (int k = 0; k < 8; k++) o[k] += bf2f(pv[k]);
    }
    const size_t grow = (size_t)(b * T_SEQ + q0 + row);
    if (g == 0) {
        float* op = O0 + grow * HD_D + dc;
#pragma unroll
        for (int k = 0; k < 8; k++) op[k] = o[k];
    } else {
        ushort8v h;
#pragma unroll
        for (int k = 0; k < 8; k++) h[k] = f2bf_fast(o[k]);
        *(ushort8v*)&O1[grow * HD_D + dc] = h;
    }
    if ((tid & 15) == 0) Lp[g * 8192 + grow] = lt;
}

// ---------------------------------------------------------------------------
// Kernel 3: combine the two k-group partials: out = (O0 + O1) / (l0 + l1)
// ---------------------------------------------------------------------------
__global__ __launch_bounds__(256) void attn_merge(
    float* __restrict__ out, const unsigned short* __restrict__ O1,
    const float* __restrict__ Lp)
{
    const int idx = blockIdx.x * 256 + threadIdx.x;   // f32x4 index (262144)
    const int row = idx >> 5;                          // 32 f32x4 per row
    f32x4 a = ((f32x4*)out)[idx];
    const ushort4v h = ((const ushort4v*)O1)[idx];
    f32x4 bv = { bf2f(h.x), bf2f(h.y), bf2f(h.z), bf2f(h.w) };
    const float inv = 1.0f / (Lp[row] + Lp[8192 + row]);
    ((f32x4*)out)[idx] = (a + bv) * inv;
}

// ---------------------------------------------------------------------------
extern "C" void kernel_launch(void* const* d_in, const int* in_sizes, int n_in,
                              void* d_out, int out_size, void* d_ws, size_t ws_size,
                              hipStream_t stream)
{
    (void)in_sizes; (void)n_in; (void)out_size; (void)ws_size;
    const float* x  = (const float*)d_in[0];
    const float* Wq = (const float*)d_in[1];
    const float* Wk = (const float*)d_in[2];
    const float* Wv = (const float*)d_in[3];
    const float* rc = (const float*)d_in[4];
    const float* rs = (const float*)d_in[5];
    // d_in[6] = additive causal mask: handled analytically, not read.
    float* out = (float*)d_out;

    char* ws = (char*)d_ws;
    unsigned short* Wt = (unsigned short*)(ws);                    // 1,572,864 B
    unsigned short* Qb = (unsigned short*)(ws + 1572864);          // 2,097,152 B
    unsigned short* Kb = (unsigned short*)(ws + 3670016);          // 2,097,152 B
    unsigned short* Vt = (unsigned short*)(ws + 5767168);          // 2,097,152 B
    unsigned short* O1 = (unsigned short*)(ws + 7864320);          // 2,097,152 B
    float*          Lp = (float*)(ws + 9961472);                   //    65,536 B

    prep_weights<<<dim3(32, 3), 256, 0, stream>>>(Wq, Wk, Wv, Wt);
    qkv_fused   <<<dim3(512),   256, 0, stream>>>(x, Wt, rc, rs, Qb, Kb, Vt);
    attn        <<<dim3(1024),  256, 0, stream>>>(Qb, Kb, Vt, out, O1, Lp);
    attn_merge  <<<dim3(1024),  256, 0, stream>>>(out, O1, Lp);
}

// Round 11
// 195.863 us; speedup vs baseline: 1.1708x; 1.1708x over previous
//
#include <hip/hip_runtime.h>
#include <cstddef>
#include <cstdint>

#define T_SEQ 2048
#define EMB_D 2048
#define HD_D  128

typedef __attribute__((ext_vector_type(8))) short short8;
typedef __attribute__((ext_vector_type(4))) float f32x4;
typedef __attribute__((ext_vector_type(4))) unsigned short ushort4v;
typedef __attribute__((ext_vector_type(8))) unsigned short ushort8v;

union frag_u { short8 s8; unsigned u[4]; };

static __device__ __forceinline__ unsigned short f2bf_rne(float f) {
    union { float f; unsigned u; } v; v.f = f;
    unsigned r = v.u + 0x7fffu + ((v.u >> 16) & 1u);
    return (unsigned short)(r >> 16);
}
static __device__ __forceinline__ unsigned short f2bf_fast(float f) {
    union { float f; unsigned u; } v; v.f = f;
    return (unsigned short)((v.u + 0x8000u) >> 16);
}
// pack two fp32 -> packed bf16 pair (round-half-up) in 3 VALU
static __device__ __forceinline__ unsigned pk2(float a, float b) {
    union { float f; unsigned u; } x, y; x.f = a; y.f = b;
    return __builtin_amdgcn_perm(y.u + 0x8000u, x.u + 0x8000u, 0x07060302);
}
static __device__ __forceinline__ void dma16(const void* g, void* l) {
    __builtin_amdgcn_global_load_lds(
        (const __attribute__((address_space(1))) unsigned int*)g,
        (__attribute__((address_space(3))) unsigned int*)l, 16, 0, 0);
}
#define EXP2F(x) __builtin_amdgcn_exp2f(x)

// ---------------------------------------------------------------------------
// Kernel 0: coalesced transpose + bf16 convert: Wt[w][n][k] = W_w[k][n]
// ---------------------------------------------------------------------------
__global__ __launch_bounds__(256) void prep_weights(
    const float* __restrict__ Wq, const float* __restrict__ Wk,
    const float* __restrict__ Wv, unsigned short* __restrict__ Wt)
{
    __shared__ __attribute__((aligned(16))) unsigned short tw[64 * 132];
    const int w = blockIdx.y;
    const int k0 = blockIdx.x * 64;
    const float* W = (w == 0) ? Wq : (w == 1) ? Wk : Wv;
    const int tid = threadIdx.x;
#pragma unroll
    for (int p = 0; p < 8; p++) {
        const int f = p * 256 + tid;        // float4 index over 64x32
        const int row = f >> 5, c4 = f & 31;
        const float4 v = *(const float4*)&W[(size_t)(k0 + row) * HD_D + c4 * 4];
        ushort4v h = { f2bf_rne(v.x), f2bf_rne(v.y), f2bf_rne(v.z), f2bf_rne(v.w) };
        *(ushort4v*)&tw[row * 132 + c4 * 4] = h;
    }
    __syncthreads();
    const int n = tid >> 1, h = tid & 1;
    unsigned short* dst = Wt + (size_t)w * (HD_D * EMB_D) + (size_t)n * EMB_D + k0 + h * 32;
#pragma unroll
    for (int j = 0; j < 4; j++) {
        ushort8v o;
#pragma unroll
        for (int jj = 0; jj < 8; jj++) o[jj] = tw[(h * 32 + j * 8 + jj) * 132 + n];
        *(ushort8v*)&dst[j * 8] = o;
    }
}

// ---------------------------------------------------------------------------
// Kernel 1: FUSED QKV projection + RoPE (64 rows x 96 cols, DMA dbuf),
//   XCD-swizzled: all 4 column groups of one m0 land on the same XCD so x
//   is fetched from HBM once per m0 and 3x from that XCD's L2.
//   (kept from R10 — attn revert isolates its effect this round)
// ---------------------------------------------------------------------------
__global__ __launch_bounds__(256, 2) void qkv_fused(
    const float* __restrict__ x, const unsigned short* __restrict__ Wt,
    const float* __restrict__ rcos, const float* __restrict__ rsin,
    unsigned short* __restrict__ Qb, unsigned short* __restrict__ Kb,
    unsigned short* __restrict__ Vt)
{
    __shared__ __attribute__((aligned(16))) float xs[2][64 * 64];            // 2 x 16 KB
    __shared__ __attribute__((aligned(16))) unsigned short wsb[2][96 * 64];  // 2 x 12 KB
    const int L = blockIdx.x;
    const int xcd = L & 7, s = L >> 3;
    const int ng = s & 3;                       // column group (same-xcd for fixed m0)
    const int m0 = (xcd * 16 + (s >> 2)) * 64;  // 128 m-tiles spread across XCDs
    const int tid = threadIdx.x;
    const int lane = tid & 63, wave = tid >> 6;
    const int wm = wave >> 1, wn = wave & 1;    // 2x2 wave grid: 32 rows x 48 cols
    const int l15 = lane & 15, lq = lane >> 4;

    // --- x DMA: 1024 granules (64 rows x 16 x 16B), 4 per thread ---
    const float* xSrc[4]; int xOff[4];
#pragma unroll
    for (int p = 0; p < 4; p++) {
        const int g = p * 256 + tid;
        const int row = g >> 4, c = g & 15;
        xSrc[p] = x + (size_t)(m0 + row) * EMB_D + (c ^ (row & 15)) * 4;
        xOff[p] = (p * 256 + wave * 64) * 4;
    }
    // --- W DMA: 768 granules (96 rows x 8 x 16B), 3 per thread ---
    const unsigned short* wSrc[3]; int wOff[3];
#pragma unroll
    for (int p = 0; p < 3; p++) {
        const int g = p * 256 + tid;
        const int row = g >> 3, c = g & 7;
        wSrc[p] = Wt + (size_t)(ng * 96 + row) * EMB_D + (c ^ (row & 7)) * 8;
        wOff[p] = (p * 256 + wave * 64) * 8;
    }

    int offA[2][2][2];
#pragma unroll
    for (int i = 0; i < 2; i++)
#pragma unroll
        for (int ks = 0; ks < 2; ks++) {
            const int row = wm * 32 + i * 16 + l15;
            const int ga = ks * 8 + lq * 2;
            offA[i][ks][0] = row * 64 + ((ga)     ^ (row & 15)) * 4;
            offA[i][ks][1] = row * 64 + ((ga + 1) ^ (row & 15)) * 4;
        }
    int offB[3][2];
#pragma unroll
    for (int j = 0; j < 3; j++)
#pragma unroll
        for (int ks = 0; ks < 2; ks++) {
            const int row = wn * 48 + j * 16 + l15;
            const int gb = ks * 4 + lq;
            offB[j][ks] = row * 64 + (gb ^ (row & 7)) * 8;
        }

    f32x4 acc[2][3];
#pragma unroll
    for (int i = 0; i < 2; i++)
#pragma unroll
        for (int j = 0; j < 3; j++) acc[i][j] = (f32x4){0.f, 0.f, 0.f, 0.f};

#pragma unroll
    for (int p = 0; p < 4; p++) dma16(xSrc[p], &xs[0][xOff[p]]);
#pragma unroll
    for (int p = 0; p < 3; p++) dma16(wSrc[p], &wsb[0][wOff[p]]);

    for (int k0 = 0; k0 < EMB_D; k0 += 64) {
        const int buf = (k0 >> 6) & 1;
        __syncthreads();   // vmcnt(0): drains buf's DMA (issued one compute-phase ago)
        if (k0 + 64 < EMB_D) {
#pragma unroll
            for (int p = 0; p < 4; p++)
                dma16(xSrc[p] + k0 + 64, &xs[buf ^ 1][xOff[p]]);
#pragma unroll
            for (int p = 0; p < 3; p++)
                dma16(wSrc[p] + k0 + 64, &wsb[buf ^ 1][wOff[p]]);
        }

        frag_u A[2][2];
#pragma unroll
        for (int i = 0; i < 2; i++)
#pragma unroll
            for (int ks = 0; ks < 2; ks++) {
                const f32x4 f0 = *(const f32x4*)&xs[buf][offA[i][ks][0]];
                const f32x4 f1 = *(const f32x4*)&xs[buf][offA[i][ks][1]];
                A[i][ks].u[0] = pk2(f0.x, f0.y);
                A[i][ks].u[1] = pk2(f0.z, f0.w);
                A[i][ks].u[2] = pk2(f1.x, f1.y);
                A[i][ks].u[3] = pk2(f1.z, f1.w);
            }
#pragma unroll
        for (int ks = 0; ks < 2; ks++)
#pragma unroll
            for (int j = 0; j < 3; j++) {
                const short8 B = *(const short8*)&wsb[buf][offB[j][ks]];
#pragma unroll
                for (int i = 0; i < 2; i++)
                    acc[i][j] = __builtin_amdgcn_mfma_f32_16x16x32_bf16(
                        A[i][ks].s8, B, acc[i][j], 0, 0, 0);
            }
    }

    const float qscale = 0.08838834764831845f * 1.4426950408889634f; // 1/sqrt(128)*log2(e)
#pragma unroll
    for (int i = 0; i < 2; i++) {
#pragma unroll
        for (int r = 0; r < 4; r++) {
            const int row = m0 + wm * 32 + i * 16 + lq * 4 + r;   // b*T + t
            const int t = row & (T_SEQ - 1);
            const int bb = row >> 11;
#pragma unroll
            for (int j = 0; j < 3; j++) {
                const int col = ng * 96 + wn * 48 + j * 16 + l15;
                const int mat = col >> 7, mcol = col & 127;
                const float v = acc[i][j][r];
                if (mat == 2) {
                    Vt[((size_t)bb * HD_D + mcol) * T_SEQ + t] = f2bf_rne(v);
                } else {
                    const int ip = mcol >> 1;
                    const float c = rcos[t * 64 + ip];
                    const float s2 = rsin[t * 64 + ip];
                    const float pv = __shfl_xor(v, 1);
                    float rv = (mcol & 1) ? (pv * s2 + v * c) : (v * c - pv * s2);
                    if (mat == 0) {
                        rv *= qscale;
                        Qb[(size_t)row * HD_D + mcol] = f2bf_rne(rv);
                    } else {
                        Kb[(size_t)row * HD_D + mcol] = f2bf_rne(rv);
                    }
                }
            }
        }
    }
}

// ---------------------------------------------------------------------------
// Kernel 2: flash attention, causal, STATIC-MAX softmax (exp2 domain) —
//   EXACT R9 structure restored (R10's split-K spilled: VGPR capped 64,
//   WRITE 92 MB scratch). 256 thr, 4-wave in-block k-split, dual-chunk ILP,
//   plain-sum merge, direct normalized fp32 out. Grid 512, bounds (256,2).
// ---------------------------------------------------------------------------
__global__ __launch_bounds__(256, 2) void attn(
    const unsigned short* __restrict__ Qb, const unsigned short* __restrict__ Kb,
    const unsigned short* __restrict__ Vt, float* __restrict__ out)
{
    __shared__ float O_s[4][16 * 128];                                         // 32 KB
    __shared__ __attribute__((aligned(16))) unsigned short P_s[4][2][16 * 40]; // 10 KB
    __shared__ float l_s[4][16];

    const int tid = threadIdx.x;
    const int lane = tid & 63, wave = tid >> 6;
    const int l15 = lane & 15, lq = lane >> 4;
    const int kf = lq * 8;

    const int b  = blockIdx.x & 3;
    const int q0 = (127 - (blockIdx.x >> 2)) * 16;   // heavy q-tiles first
    const int kend = q0 + 16;
    const float M2 = 16.0f;                          // static max (exp2 domain)

    const unsigned short* Qp = Qb + (size_t)(b * T_SEQ + q0) * HD_D;
    short8 aQ[4];
#pragma unroll
    for (int d = 0; d < 4; d++)
        aQ[d] = *(const short8*)&Qp[l15 * HD_D + d * 32 + kf];

    f32x4 acc[8];
#pragma unroll
    for (int d = 0; d < 8; d++) acc[d] = (f32x4){0.f, 0.f, 0.f, 0.f};
    float l_r[4] = {0.f, 0.f, 0.f, 0.f};

    const unsigned short* Kbase = Kb + (size_t)b * T_SEQ * HD_D;
    const unsigned short* Vbase = Vt + (size_t)b * HD_D * T_SEQ;
    unsigned short* PwA = &P_s[wave][0][0];
    unsigned short* PwB = &P_s[wave][1][0];

    for (int c = wave; c * 32 < kend; c += 8) {
        const int kA = c * 32;
        const int kB = (c + 4) * 32;
        const bool hB = kB < kend;

        const unsigned short* KpA = Kbase + (size_t)kA * HD_D;
        const unsigned short* KpB = Kbase + (size_t)kB * HD_D;
        short8 KA[8], KB_[8];
#pragma unroll
        for (int d = 0; d < 4; d++)
#pragma unroll
            for (int n = 0; n < 2; n++)
                KA[d * 2 + n] = *(const short8*)&KpA[(size_t)(n * 16 + l15) * HD_D + d * 32 + kf];
        if (hB) {
#pragma unroll
            for (int d = 0; d < 4; d++)
#pragma unroll
                for (int n = 0; n < 2; n++)
                    KB_[d * 2 + n] = *(const short8*)&KpB[(size_t)(n * 16 + l15) * HD_D + d * 32 + kf];
        }

        f32x4 sA0 = (f32x4){0.f, 0.f, 0.f, 0.f}, sA1 = sA0, sB0 = sA0, sB1 = sA0;
#pragma unroll
        for (int d = 0; d < 4; d++) {
            sA0 = __builtin_amdgcn_mfma_f32_16x16x32_bf16(aQ[d], KA[d * 2 + 0], sA0, 0, 0, 0);
            sA1 = __builtin_amdgcn_mfma_f32_16x16x32_bf16(aQ[d], KA[d * 2 + 1], sA1, 0, 0, 0);
        }
        if (hB) {
#pragma unroll
            for (int d = 0; d < 4; d++) {
                sB0 = __builtin_amdgcn_mfma_f32_16x16x32_bf16(aQ[d], KB_[d * 2 + 0], sB0, 0, 0, 0);
                sB1 = __builtin_amdgcn_mfma_f32_16x16x32_bf16(aQ[d], KB_[d * 2 + 1], sB1, 0, 0, 0);
            }
        }

        short8 VA[8];
#pragma unroll
        for (int d = 0; d < 8; d++)
            VA[d] = *(const short8*)&Vbase[(size_t)(d * 16 + l15) * T_SEQ + kA + kf];

#pragma unroll
        for (int r = 0; r < 4; r++) {
            const int q = q0 + lq * 4 + r;
            const float p0 = ((kA + l15)      <= q) ? EXP2F(sA0[r] - M2) : 0.f;
            const float p1 = ((kA + 16 + l15) <= q) ? EXP2F(sA1[r] - M2) : 0.f;
            l_r[r] += p0 + p1;
            const int prow = (lq * 4 + r) * 40;
            PwA[prow + l15]      = f2bf_fast(p0);
            PwA[prow + 16 + l15] = f2bf_fast(p1);
        }
        const short8 pA = *(const short8*)&PwA[l15 * 40 + kf];
#pragma unroll
        for (int d = 0; d < 8; d++)
            acc[d] = __builtin_amdgcn_mfma_f32_16x16x32_bf16(pA, VA[d], acc[d], 0, 0, 0);

        if (hB) {
            short8 VB[8];
#pragma unroll
            for (int d = 0; d < 8; d++)
                VB[d] = *(const short8*)&Vbase[(size_t)(d * 16 + l15) * T_SEQ + kB + kf];
#pragma unroll
            for (int r = 0; r < 4; r++) {
                const int q = q0 + lq * 4 + r;
                const float p0 = ((kB + l15)      <= q) ? EXP2F(sB0[r] - M2) : 0.f;
                const float p1 = ((kB + 16 + l15) <= q) ? EXP2F(sB1[r] - M2) : 0.f;
                l_r[r] += p0 + p1;
                const int prow = (lq * 4 + r) * 40;
                PwB[prow + l15]      = f2bf_fast(p0);
                PwB[prow + 16 + l15] = f2bf_fast(p1);
            }
            const short8 pB = *(const short8*)&PwB[l15 * 40 + kf];
#pragma unroll
            for (int d = 0; d < 8; d++)
                acc[d] = __builtin_amdgcn_mfma_f32_16x16x32_bf16(pB, VB[d], acc[d], 0, 0, 0);
        }
    }

#pragma unroll
    for (int r = 0; r < 4; r++) {
        float lr = l_r[r];
        lr += __shfl_xor(lr, 1);
        lr += __shfl_xor(lr, 2);
        lr += __shfl_xor(lr, 4);
        lr += __shfl_xor(lr, 8);
        if (l15 == 0) l_s[wave][lq * 4 + r] = lr;
#pragma unroll
        for (int d = 0; d < 8; d++)
            O_s[wave][(lq * 4 + r) * 128 + d * 16 + l15] = acc[d][r];
    }
    __syncthreads();

    const int row = tid >> 4;
    const int dc = (tid & 15) * 8;
    const float lt = l_s[0][row] + l_s[1][row] + l_s[2][row] + l_s[3][row];
    const float inv = 1.0f / lt;
    f32x4 o0 = (f32x4){0.f, 0.f, 0.f, 0.f};
    f32x4 o1 = (f32x4){0.f, 0.f, 0.f, 0.f};
#pragma unroll
    for (int w2 = 0; w2 < 4; w2++) {
        const float* p = &O_s[w2][row * 128 + dc];
        o0 += *(const f32x4*)p;
        o1 += *(const f32x4*)(p + 4);
    }
    float* op = out + (size_t)(b * T_SEQ + q0 + row) * HD_D + dc;
    *(f32x4*)op       = o0 * inv;
    *(f32x4*)(op + 4) = o1 * inv;
}

// ---------------------------------------------------------------------------
extern "C" void kernel_launch(void* const* d_in, const int* in_sizes, int n_in,
                              void* d_out, int out_size, void* d_ws, size_t ws_size,
                              hipStream_t stream)
{
    (void)in_sizes; (void)n_in; (void)out_size; (void)ws_size;
    const float* x  = (const float*)d_in[0];
    const float* Wq = (const float*)d_in[1];
    const float* Wk = (const float*)d_in[2];
    const float* Wv = (const float*)d_in[3];
    const float* rc = (const float*)d_in[4];
    const float* rs = (const float*)d_in[5];
    // d_in[6] = additive causal mask: handled analytically, not read.
    float* out = (float*)d_out;

    char* ws = (char*)d_ws;
    unsigned short* Wt = (unsigned short*)(ws);                    // 1,572,864 B
    unsigned short* Qb = (unsigned short*)(ws + 1572864);          // 2,097,152 B
    unsigned short* Kb = (unsigned short*)(ws + 3670016);          // 2,097,152 B
    unsigned short* Vt = (unsigned short*)(ws + 5767168);          // 2,097,152 B

    prep_weights<<<dim3(32, 3), 256, 0, stream>>>(Wq, Wk, Wv, Wt);
    qkv_fused   <<<dim3(512),   256, 0, stream>>>(x, Wt, rc, rs, Qb, Kb, Vt);
    attn        <<<dim3(512),   256, 0, stream>>>(Qb, Kb, Vt, out);
}

// Round 12
// 190.613 us; speedup vs baseline: 1.2030x; 1.0275x over previous
//
#include <hip/hip_runtime.h>
#include <cstddef>
#include <cstdint>

#define T_SEQ 2048
#define EMB_D 2048
#define HD_D  128

typedef __attribute__((ext_vector_type(8))) short short8;
typedef __attribute__((ext_vector_type(4))) float f32x4;
typedef __attribute__((ext_vector_type(4))) unsigned short ushort4v;
typedef __attribute__((ext_vector_type(8))) unsigned short ushort8v;

union frag_u { short8 s8; unsigned u[4]; };

static __device__ __forceinline__ unsigned short f2bf_rne(float f) {
    union { float f; unsigned u; } v; v.f = f;
    unsigned r = v.u + 0x7fffu + ((v.u >> 16) & 1u);
    return (unsigned short)(r >> 16);
}
static __device__ __forceinline__ unsigned short f2bf_fast(float f) {
    union { float f; unsigned u; } v; v.f = f;
    return (unsigned short)((v.u + 0x8000u) >> 16);
}
static __device__ __forceinline__ float bf2f(unsigned short h) {
    union { unsigned u; float f; } v; v.u = ((unsigned)h) << 16;
    return v.f;
}
// pack two fp32 -> packed bf16 pair (round-half-up) in 3 VALU
static __device__ __forceinline__ unsigned pk2(float a, float b) {
    union { float f; unsigned u; } x, y; x.f = a; y.f = b;
    return __builtin_amdgcn_perm(y.u + 0x8000u, x.u + 0x8000u, 0x07060302);
}
static __device__ __forceinline__ void dma16(const void* g, void* l) {
    __builtin_amdgcn_global_load_lds(
        (const __attribute__((address_space(1))) unsigned int*)g,
        (__attribute__((address_space(3))) unsigned int*)l, 16, 0, 0);
}
#define EXP2F(x) __builtin_amdgcn_exp2f(x)

// ---------------------------------------------------------------------------
// Kernel 0: coalesced transpose + bf16 convert: Wt[w][n][k] = W_w[k][n]
//   R12: output stores now coalesced — 8 consecutive lanes cover one n-row's
//   64 shorts (128 B contiguous), instead of lane-pairs 4 KB apart.
// ---------------------------------------------------------------------------
__global__ __launch_bounds__(256) void prep_weights(
    const float* __restrict__ Wq, const float* __restrict__ Wk,
    const float* __restrict__ Wv, unsigned short* __restrict__ Wt)
{
    __shared__ __attribute__((aligned(16))) unsigned short tw[64 * 132];
    const int w = blockIdx.y;
    const int k0 = blockIdx.x * 64;
    const float* W = (w == 0) ? Wq : (w == 1) ? Wk : Wv;
    const int tid = threadIdx.x;
#pragma unroll
    for (int p = 0; p < 8; p++) {
        const int f = p * 256 + tid;        // float4 index over 64x32
        const int row = f >> 5, c4 = f & 31;
        const float4 v = *(const float4*)&W[(size_t)(k0 + row) * HD_D + c4 * 4];
        ushort4v h = { f2bf_rne(v.x), f2bf_rne(v.y), f2bf_rne(v.z), f2bf_rne(v.w) };
        *(ushort4v*)&tw[row * 132 + c4 * 4] = h;
    }
    __syncthreads();
    const int kk = (tid & 7) * 8;           // 8 k per thread
#pragma unroll
    for (int p = 0; p < 4; p++) {
        const int n = p * 32 + (tid >> 3);  // 32 n-rows per pass
        ushort8v o;
#pragma unroll
        for (int jj = 0; jj < 8; jj++) o[jj] = tw[(kk + jj) * 132 + n];
        *(ushort8v*)&Wt[(size_t)w * (HD_D * EMB_D) + (size_t)n * EMB_D + k0 + kk] = o;
    }
}

// ---------------------------------------------------------------------------
// Kernel 1: FUSED QKV projection + RoPE (64 rows x 96 cols, DMA dbuf),
//   XCD-swizzled (R11, FROZEN: FETCH 41 MB = x read once, dur ~57).
// ---------------------------------------------------------------------------
__global__ __launch_bounds__(256, 2) void qkv_fused(
    const float* __restrict__ x, const unsigned short* __restrict__ Wt,
    const float* __restrict__ rcos, const float* __restrict__ rsin,
    unsigned short* __restrict__ Qb, unsigned short* __restrict__ Kb,
    unsigned short* __restrict__ Vt)
{
    __shared__ __attribute__((aligned(16))) float xs[2][64 * 64];            // 2 x 16 KB
    __shared__ __attribute__((aligned(16))) unsigned short wsb[2][96 * 64];  // 2 x 12 KB
    const int L = blockIdx.x;
    const int xcd = L & 7, s = L >> 3;
    const int ng = s & 3;                       // column group (same-xcd for fixed m0)
    const int m0 = (xcd * 16 + (s >> 2)) * 64;  // 128 m-tiles spread across XCDs
    const int tid = threadIdx.x;
    const int lane = tid & 63, wave = tid >> 6;
    const int wm = wave >> 1, wn = wave & 1;    // 2x2 wave grid: 32 rows x 48 cols
    const int l15 = lane & 15, lq = lane >> 4;

    const float* xSrc[4]; int xOff[4];
#pragma unroll
    for (int p = 0; p < 4; p++) {
        const int g = p * 256 + tid;
        const int row = g >> 4, c = g & 15;
        xSrc[p] = x + (size_t)(m0 + row) * EMB_D + (c ^ (row & 15)) * 4;
        xOff[p] = (p * 256 + wave * 64) * 4;
    }
    const unsigned short* wSrc[3]; int wOff[3];
#pragma unroll
    for (int p = 0; p < 3; p++) {
        const int g = p * 256 + tid;
        const int row = g >> 3, c = g & 7;
        wSrc[p] = Wt + (size_t)(ng * 96 + row) * EMB_D + (c ^ (row & 7)) * 8;
        wOff[p] = (p * 256 + wave * 64) * 8;
    }

    int offA[2][2][2];
#pragma unroll
    for (int i = 0; i < 2; i++)
#pragma unroll
        for (int ks = 0; ks < 2; ks++) {
            const int row = wm * 32 + i * 16 + l15;
            const int ga = ks * 8 + lq * 2;
            offA[i][ks][0] = row * 64 + ((ga)     ^ (row & 15)) * 4;
            offA[i][ks][1] = row * 64 + ((ga + 1) ^ (row & 15)) * 4;
        }
    int offB[3][2];
#pragma unroll
    for (int j = 0; j < 3; j++)
#pragma unroll
        for (int ks = 0; ks < 2; ks++) {
            const int row = wn * 48 + j * 16 + l15;
            const int gb = ks * 4 + lq;
            offB[j][ks] = row * 64 + (gb ^ (row & 7)) * 8;
        }

    f32x4 acc[2][3];
#pragma unroll
    for (int i = 0; i < 2; i++)
#pragma unroll
        for (int j = 0; j < 3; j++) acc[i][j] = (f32x4){0.f, 0.f, 0.f, 0.f};

#pragma unroll
    for (int p = 0; p < 4; p++) dma16(xSrc[p], &xs[0][xOff[p]]);
#pragma unroll
    for (int p = 0; p < 3; p++) dma16(wSrc[p], &wsb[0][wOff[p]]);

    for (int k0 = 0; k0 < EMB_D; k0 += 64) {
        const int buf = (k0 >> 6) & 1;
        __syncthreads();   // vmcnt(0): drains buf's DMA (issued one compute-phase ago)
        if (k0 + 64 < EMB_D) {
#pragma unroll
            for (int p = 0; p < 4; p++)
                dma16(xSrc[p] + k0 + 64, &xs[buf ^ 1][xOff[p]]);
#pragma unroll
            for (int p = 0; p < 3; p++)
                dma16(wSrc[p] + k0 + 64, &wsb[buf ^ 1][wOff[p]]);
        }

        frag_u A[2][2];
#pragma unroll
        for (int i = 0; i < 2; i++)
#pragma unroll
            for (int ks = 0; ks < 2; ks++) {
                const f32x4 f0 = *(const f32x4*)&xs[buf][offA[i][ks][0]];
                const f32x4 f1 = *(const f32x4*)&xs[buf][offA[i][ks][1]];
                A[i][ks].u[0] = pk2(f0.x, f0.y);
                A[i][ks].u[1] = pk2(f0.z, f0.w);
                A[i][ks].u[2] = pk2(f1.x, f1.y);
                A[i][ks].u[3] = pk2(f1.z, f1.w);
            }
#pragma unroll
        for (int ks = 0; ks < 2; ks++)
#pragma unroll
            for (int j = 0; j < 3; j++) {
                const short8 B = *(const short8*)&wsb[buf][offB[j][ks]];
#pragma unroll
                for (int i = 0; i < 2; i++)
                    acc[i][j] = __builtin_amdgcn_mfma_f32_16x16x32_bf16(
                        A[i][ks].s8, B, acc[i][j], 0, 0, 0);
            }
    }

    const float qscale = 0.08838834764831845f * 1.4426950408889634f; // 1/sqrt(128)*log2(e)
#pragma unroll
    for (int i = 0; i < 2; i++) {
#pragma unroll
        for (int r = 0; r < 4; r++) {
            const int row = m0 + wm * 32 + i * 16 + lq * 4 + r;   // b*T + t
            const int t = row & (T_SEQ - 1);
            const int bb = row >> 11;
#pragma unroll
            for (int j = 0; j < 3; j++) {
                const int col = ng * 96 + wn * 48 + j * 16 + l15;
                const int mat = col >> 7, mcol = col & 127;
                const float v = acc[i][j][r];
                if (mat == 2) {
                    Vt[((size_t)bb * HD_D + mcol) * T_SEQ + t] = f2bf_rne(v);
                } else {
                    const int ip = mcol >> 1;
                    const float c = rcos[t * 64 + ip];
                    const float s2 = rsin[t * 64 + ip];
                    const float pv = __shfl_xor(v, 1);
                    float rv = (mcol & 1) ? (pv * s2 + v * c) : (v * c - pv * s2);
                    if (mat == 0) {
                        rv *= qscale;
                        Qb[(size_t)row * HD_D + mcol] = f2bf_rne(rv);
                    } else {
                        Kb[(size_t)row * HD_D + mcol] = f2bf_rne(rv);
                    }
                }
            }
        }
    }
}

// ---------------------------------------------------------------------------
// Kernel 2: flash attention, causal, STATIC-MAX softmax, SPLIT-K v2.
//   R10 retried WITHOUT the fatal VGPR cap: bounds (256,2) (R10's (256,4)
//   forced VGPR=64 -> 92 MB scratch spill). bf16 O_s cuts LDS 42->26 KB so
//   grid 1024 can co-reside 4 blocks/CU = 16 waves/CU (2x R11's hiding).
//   Partials are plain sums (static max): g0 -> fp32 in out, g1 -> bf16+l
//   in ws; attn_merge combines.
// ---------------------------------------------------------------------------
__global__ __launch_bounds__(256, 2) void attn(
    const unsigned short* __restrict__ Qb, const unsigned short* __restrict__ Kb,
    const unsigned short* __restrict__ Vt, float* __restrict__ O0,
    unsigned short* __restrict__ O1, float* __restrict__ Lp)
{
    __shared__ __attribute__((aligned(16))) unsigned short O_s[4][16 * 128];   // 16 KB
    __shared__ __attribute__((aligned(16))) unsigned short P_s[4][2][16 * 40]; // 10 KB
    __shared__ float l_s[4][16];

    const int tid = threadIdx.x;
    const int lane = tid & 63, wave = tid >> 6;
    const int l15 = lane & 15, lq = lane >> 4;
    const int kf = lq * 8;

    const int L = blockIdx.x;
    const int g = L & 1;                         // k-group
    const int b = (L >> 1) & 3;
    const int q0 = (127 - (L >> 3)) * 16;        // heavy q-tiles first
    const int kend = q0 + 16;
    const float M2 = 16.0f;                      // static max (exp2 domain)

    const unsigned short* Qp = Qb + (size_t)(b * T_SEQ + q0) * HD_D;
    short8 aQ[4];
#pragma unroll
    for (int d = 0; d < 4; d++)
        aQ[d] = *(const short8*)&Qp[l15 * HD_D + d * 32 + kf];

    f32x4 acc[8];
#pragma unroll
    for (int d = 0; d < 8; d++) acc[d] = (f32x4){0.f, 0.f, 0.f, 0.f};
    float l_r[4] = {0.f, 0.f, 0.f, 0.f};

    const unsigned short* Kbase = Kb + (size_t)b * T_SEQ * HD_D;
    const unsigned short* Vbase = Vt + (size_t)b * HD_D * T_SEQ;
    unsigned short* PwA = &P_s[wave][0][0];
    unsigned short* PwB = &P_s[wave][1][0];

    // chunk residues: A covers c%16 in {0..7}, B covers {8..15} (over wave,g)
    for (int c = 2 * wave + g; c * 32 < kend; c += 16) {
        const int kA = c * 32;
        const int kB = (c + 8) * 32;
        const bool hB = kB < kend;

        const unsigned short* KpA = Kbase + (size_t)kA * HD_D;
        const unsigned short* KpB = Kbase + (size_t)kB * HD_D;
        short8 KA[8], KB_[8];
#pragma unroll
        for (int d = 0; d < 4; d++)
#pragma unroll
            for (int n = 0; n < 2; n++)
                KA[d * 2 + n] = *(const short8*)&KpA[(size_t)(n * 16 + l15) * HD_D + d * 32 + kf];
        if (hB) {
#pragma unroll
            for (int d = 0; d < 4; d++)
#pragma unroll
                for (int n = 0; n < 2; n++)
                    KB_[d * 2 + n] = *(const short8*)&KpB[(size_t)(n * 16 + l15) * HD_D + d * 32 + kf];
        }

        f32x4 sA0 = (f32x4){0.f, 0.f, 0.f, 0.f}, sA1 = sA0, sB0 = sA0, sB1 = sA0;
#pragma unroll
        for (int d = 0; d < 4; d++) {
            sA0 = __builtin_amdgcn_mfma_f32_16x16x32_bf16(aQ[d], KA[d * 2 + 0], sA0, 0, 0, 0);
            sA1 = __builtin_amdgcn_mfma_f32_16x16x32_bf16(aQ[d], KA[d * 2 + 1], sA1, 0, 0, 0);
        }
        if (hB) {
#pragma unroll
            for (int d = 0; d < 4; d++) {
                sB0 = __builtin_amdgcn_mfma_f32_16x16x32_bf16(aQ[d], KB_[d * 2 + 0], sB0, 0, 0, 0);
                sB1 = __builtin_amdgcn_mfma_f32_16x16x32_bf16(aQ[d], KB_[d * 2 + 1], sB1, 0, 0, 0);
            }
        }

        short8 VA[8];
#pragma unroll
        for (int d = 0; d < 8; d++)
            VA[d] = *(const short8*)&Vbase[(size_t)(d * 16 + l15) * T_SEQ + kA + kf];

#pragma unroll
        for (int r = 0; r < 4; r++) {
            const int q = q0 + lq * 4 + r;
            const float p0 = ((kA + l15)      <= q) ? EXP2F(sA0[r] - M2) : 0.f;
            const float p1 = ((kA + 16 + l15) <= q) ? EXP2F(sA1[r] - M2) : 0.f;
            l_r[r] += p0 + p1;
            const int prow = (lq * 4 + r) * 40;
            PwA[prow + l15]      = f2bf_fast(p0);
            PwA[prow + 16 + l15] = f2bf_fast(p1);
        }
        const short8 pA = *(const short8*)&PwA[l15 * 40 + kf];
#pragma unroll
        for (int d = 0; d < 8; d++)
            acc[d] = __builtin_amdgcn_mfma_f32_16x16x32_bf16(pA, VA[d], acc[d], 0, 0, 0);

        if (hB) {
            short8 VB[8];
#pragma unroll
            for (int d = 0; d < 8; d++)
                VB[d] = *(const short8*)&Vbase[(size_t)(d * 16 + l15) * T_SEQ + kB + kf];
#pragma unroll
            for (int r = 0; r < 4; r++) {
                const int q = q0 + lq * 4 + r;
                const float p0 = ((kB + l15)      <= q) ? EXP2F(sB0[r] - M2) : 0.f;
                const float p1 = ((kB + 16 + l15) <= q) ? EXP2F(sB1[r] - M2) : 0.f;
                l_r[r] += p0 + p1;
                const int prow = (lq * 4 + r) * 40;
                PwB[prow + l15]      = f2bf_fast(p0);
                PwB[prow + 16 + l15] = f2bf_fast(p1);
            }
            const short8 pB = *(const short8*)&PwB[l15 * 40 + kf];
#pragma unroll
            for (int d = 0; d < 8; d++)
                acc[d] = __builtin_amdgcn_mfma_f32_16x16x32_bf16(pB, VB[d], acc[d], 0, 0, 0);
        }
    }

    // ---- in-block 4-way merge (plain sums), write UNNORMALIZED partial ----
#pragma unroll
    for (int r = 0; r < 4; r++) {
        float lr = l_r[r];
        lr += __shfl_xor(lr, 1);
        lr += __shfl_xor(lr, 2);
        lr += __shfl_xor(lr, 4);
        lr += __shfl_xor(lr, 8);
        if (l15 == 0) l_s[wave][lq * 4 + r] = lr;
#pragma unroll
        for (int d = 0; d < 8; d++)
            O_s[wave][(lq * 4 + r) * 128 + d * 16 + l15] = f2bf_fast(acc[d][r]);
    }
    __syncthreads();

    const int row = tid >> 4;
    const int dc = (tid & 15) * 8;
    const float lt = l_s[0][row] + l_s[1][row] + l_s[2][row] + l_s[3][row];
    float o[8];
#pragma unroll
    for (int k = 0; k < 8; k++) o[k] = 0.f;
#pragma unroll
    for (int w2 = 0; w2 < 4; w2++) {
        const ushort8v pv = *(const ushort8v*)&O_s[w2][row * 128 + dc];
#pragma unroll
        for (int k = 0; k < 8; k++) o[k] += bf2f(pv[k]);
    }
    const size_t grow = (size_t)(b * T_SEQ + q0 + row);
    if (g == 0) {
        float* op = O0 + grow * HD_D + dc;
#pragma unroll
        for (int k = 0; k < 8; k++) op[k] = o[k];
    } else {
        ushort8v h;
#pragma unroll
        for (int k = 0; k < 8; k++) h[k] = f2bf_fast(o[k]);
        *(ushort8v*)&O1[grow * HD_D + dc] = h;
    }
    if ((tid & 15) == 0) Lp[g * 8192 + grow] = lt;
}

// ---------------------------------------------------------------------------
// Kernel 3: combine the two k-group partials: out = (O0 + O1) / (l0 + l1)
// ---------------------------------------------------------------------------
__global__ __launch_bounds__(256) void attn_merge(
    float* __restrict__ out, const unsigned short* __restrict__ O1,
    const float* __restrict__ Lp)
{
    const int idx = blockIdx.x * 256 + threadIdx.x;   // f32x4 index (262144)
    const int row = idx >> 5;                          // 32 f32x4 per row
    f32x4 a = ((f32x4*)out)[idx];
    const ushort4v h = ((const ushort4v*)O1)[idx];
    f32x4 bv = { bf2f(h.x), bf2f(h.y), bf2f(h.z), bf2f(h.w) };
    const float inv = 1.0f / (Lp[row] + Lp[8192 + row]);
    ((f32x4*)out)[idx] = (a + bv) * inv;
}

// ---------------------------------------------------------------------------
extern "C" void kernel_launch(void* const* d_in, const int* in_sizes, int n_in,
                              void* d_out, int out_size, void* d_ws, size_t ws_size,
                              hipStream_t stream)
{
    (void)in_sizes; (void)n_in; (void)out_size; (void)ws_size;
    const float* x  = (const float*)d_in[0];
    const float* Wq = (const float*)d_in[1];
    const float* Wk = (const float*)d_in[2];
    const float* Wv = (const float*)d_in[3];
    const float* rc = (const float*)d_in[4];
    const float* rs = (const float*)d_in[5];
    // d_in[6] = additive causal mask: handled analytically, not read.
    float* out = (float*)d_out;

    char* ws = (char*)d_ws;
    unsigned short* Wt = (unsigned short*)(ws);                    // 1,572,864 B
    unsigned short* Qb = (unsigned short*)(ws + 1572864);          // 2,097,152 B
    unsigned short* Kb = (unsigned short*)(ws + 3670016);          // 2,097,152 B
    unsigned short* Vt = (unsigned short*)(ws + 5767168);          // 2,097,152 B
    unsigned short* O1 = (unsigned short*)(ws + 7864320);          // 2,097,152 B
    float*          Lp = (float*)(ws + 9961472);                   //    65,536 B

    prep_weights<<<dim3(32, 3), 256, 0, stream>>>(Wq, Wk, Wv, Wt);
    qkv_fused   <<<dim3(512),   256, 0, stream>>>(x, Wt, rc, rs, Qb, Kb, Vt);
    attn        <<<dim3(1024),  256, 0, stream>>>(Qb, Kb, Vt, out, O1, Lp);
    attn_merge  <<<dim3(1024),  256, 0, stream>>>(out, O1, Lp);
}

// Round 13
// 188.762 us; speedup vs baseline: 1.2148x; 1.0098x over previous
//
#include <hip/hip_runtime.h>
#include <cstddef>
#include <cstdint>

#define T_SEQ 2048
#define EMB_D 2048
#define HD_D  128

typedef __attribute__((ext_vector_type(8))) short short8;
typedef __attribute__((ext_vector_type(4))) float f32x4;
typedef __attribute__((ext_vector_type(4))) unsigned short ushort4v;
typedef __attribute__((ext_vector_type(8))) unsigned short ushort8v;

union frag_u { short8 s8; unsigned u[4]; };

static __device__ __forceinline__ unsigned short f2bf_rne(float f) {
    union { float f; unsigned u; } v; v.f = f;
    unsigned r = v.u + 0x7fffu + ((v.u >> 16) & 1u);
    return (unsigned short)(r >> 16);
}
static __device__ __forceinline__ unsigned short f2bf_fast(float f) {
    union { float f; unsigned u; } v; v.f = f;
    return (unsigned short)((v.u + 0x8000u) >> 16);
}
static __device__ __forceinline__ float bf2f(unsigned short h) {
    union { unsigned u; float f; } v; v.u = ((unsigned)h) << 16;
    return v.f;
}
// pack two fp32 -> packed bf16 pair (round-half-up) in 3 VALU
static __device__ __forceinline__ unsigned pk2(float a, float b) {
    union { float f; unsigned u; } x, y; x.f = a; y.f = b;
    return __builtin_amdgcn_perm(y.u + 0x8000u, x.u + 0x8000u, 0x07060302);
}
static __device__ __forceinline__ void dma16(const void* g, void* l) {
    __builtin_amdgcn_global_load_lds(
        (const __attribute__((address_space(1))) unsigned int*)g,
        (__attribute__((address_space(3))) unsigned int*)l, 16, 0, 0);
}
#define EXP2F(x) __builtin_amdgcn_exp2f(x)

// ---------------------------------------------------------------------------
// Kernel 0: coalesced transpose + bf16 convert: Wt[w][n][k] = W_w[k][n]
//   (R12 coalesced-store version, frozen)
// ---------------------------------------------------------------------------
__global__ __launch_bounds__(256) void prep_weights(
    const float* __restrict__ Wq, const float* __restrict__ Wk,
    const float* __restrict__ Wv, unsigned short* __restrict__ Wt)
{
    __shared__ __attribute__((aligned(16))) unsigned short tw[64 * 132];
    const int w = blockIdx.y;
    const int k0 = blockIdx.x * 64;
    const float* W = (w == 0) ? Wq : (w == 1) ? Wk : Wv;
    const int tid = threadIdx.x;
#pragma unroll
    for (int p = 0; p < 8; p++) {
        const int f = p * 256 + tid;        // float4 index over 64x32
        const int row = f >> 5, c4 = f & 31;
        const float4 v = *(const float4*)&W[(size_t)(k0 + row) * HD_D + c4 * 4];
        ushort4v h = { f2bf_rne(v.x), f2bf_rne(v.y), f2bf_rne(v.z), f2bf_rne(v.w) };
        *(ushort4v*)&tw[row * 132 + c4 * 4] = h;
    }
    __syncthreads();
    const int kk = (tid & 7) * 8;           // 8 k per thread
#pragma unroll
    for (int p = 0; p < 4; p++) {
        const int n = p * 32 + (tid >> 3);  // 32 n-rows per pass
        ushort8v o;
#pragma unroll
        for (int jj = 0; jj < 8; jj++) o[jj] = tw[(kk + jj) * 132 + n];
        *(ushort8v*)&Wt[(size_t)w * (HD_D * EMB_D) + (size_t)n * EMB_D + k0 + kk] = o;
    }
}

// ---------------------------------------------------------------------------
// Kernel 1: FUSED QKV projection + RoPE, triple-buffered x DMA.
//   R13: the invariant killing qkv (56 µs across R6-R12) was the vmcnt(0)
//   drain at __syncthreads — the x DMA (HBM, ~900 cyc) only ever got one
//   ~300-cyc compute phase of flight. Now: x triple-buffered (issued 2 iters
//   ahead), W double-buffered (L2, 1 iter ahead), barrier = raw
//   `s_waitcnt vmcnt(4); s_barrier` so the newest x stays in flight across
//   the barrier (m139 pattern). Issue order per iter: W(j+1) then x(j+2) ->
//   oldest 7 outstanding at barrier j are exactly x(j)+W(j). Final iter
//   peeled with vmcnt(0). LDS 72 KB -> 2 blocks/CU. XCD swizzle kept.
// ---------------------------------------------------------------------------
__global__ __launch_bounds__(256, 2) void qkv_fused(
    const float* __restrict__ x, const unsigned short* __restrict__ Wt,
    const float* __restrict__ rcos, const float* __restrict__ rsin,
    unsigned short* __restrict__ Qb, unsigned short* __restrict__ Kb,
    unsigned short* __restrict__ Vt)
{
    __shared__ __attribute__((aligned(16))) float xs[3][64 * 64];            // 3 x 16 KB
    __shared__ __attribute__((aligned(16))) unsigned short wsb[2][96 * 64];  // 2 x 12 KB
    const int L = blockIdx.x;
    const int xcd = L & 7, s = L >> 3;
    const int ng = s & 3;                       // column group (same-xcd for fixed m0)
    const int m0 = (xcd * 16 + (s >> 2)) * 64;  // 128 m-tiles spread across XCDs
    const int tid = threadIdx.x;
    const int lane = tid & 63, wave = tid >> 6;
    const int wm = wave >> 1, wn = wave & 1;    // 2x2 wave grid: 32 rows x 48 cols
    const int l15 = lane & 15, lq = lane >> 4;

    const float* xSrc[4]; int xOff[4];
#pragma unroll
    for (int p = 0; p < 4; p++) {
        const int g = p * 256 + tid;
        const int row = g >> 4, c = g & 15;
        xSrc[p] = x + (size_t)(m0 + row) * EMB_D + (c ^ (row & 15)) * 4;
        xOff[p] = (p * 256 + wave * 64) * 4;
    }
    const unsigned short* wSrc[3]; int wOff[3];
#pragma unroll
    for (int p = 0; p < 3; p++) {
        const int g = p * 256 + tid;
        const int row = g >> 3, c = g & 7;
        wSrc[p] = Wt + (size_t)(ng * 96 + row) * EMB_D + (c ^ (row & 7)) * 8;
        wOff[p] = (p * 256 + wave * 64) * 8;
    }

    int offA[2][2][2];
#pragma unroll
    for (int i = 0; i < 2; i++)
#pragma unroll
        for (int ks = 0; ks < 2; ks++) {
            const int row = wm * 32 + i * 16 + l15;
            const int ga = ks * 8 + lq * 2;
            offA[i][ks][0] = row * 64 + ((ga)     ^ (row & 15)) * 4;
            offA[i][ks][1] = row * 64 + ((ga + 1) ^ (row & 15)) * 4;
        }
    int offB[3][2];
#pragma unroll
    for (int j = 0; j < 3; j++)
#pragma unroll
        for (int ks = 0; ks < 2; ks++) {
            const int row = wn * 48 + j * 16 + l15;
            const int gb = ks * 4 + lq;
            offB[j][ks] = row * 64 + (gb ^ (row & 7)) * 8;
        }

    f32x4 acc[2][3];
#pragma unroll
    for (int i = 0; i < 2; i++)
#pragma unroll
        for (int j = 0; j < 3; j++) acc[i][j] = (f32x4){0.f, 0.f, 0.f, 0.f};

    // ---- prologue: x(0) -> slot0, W(0) -> slot0, x(1) -> slot1 (this order!)
#pragma unroll
    for (int p = 0; p < 4; p++) dma16(xSrc[p], &xs[0][xOff[p]]);
#pragma unroll
    for (int p = 0; p < 3; p++) dma16(wSrc[p], &wsb[0][wOff[p]]);
#pragma unroll
    for (int p = 0; p < 4; p++) dma16(xSrc[p] + 64, &xs[1][xOff[p]]);

#define QKV_COMPUTE(XB, WB)                                                    \
    do {                                                                       \
        frag_u A[2][2];                                                        \
        _Pragma("unroll")                                                      \
        for (int i = 0; i < 2; i++)                                            \
            _Pragma("unroll")                                                  \
            for (int ks = 0; ks < 2; ks++) {                                   \
                const f32x4 f0 = *(const f32x4*)&xs[XB][offA[i][ks][0]];       \
                const f32x4 f1 = *(const f32x4*)&xs[XB][offA[i][ks][1]];       \
                A[i][ks].u[0] = pk2(f0.x, f0.y);                               \
                A[i][ks].u[1] = pk2(f0.z, f0.w);                               \
                A[i][ks].u[2] = pk2(f1.x, f1.y);                               \
                A[i][ks].u[3] = pk2(f1.z, f1.w);                               \
            }                                                                  \
        _Pragma("unroll")                                                      \
        for (int ks = 0; ks < 2; ks++)                                         \
            _Pragma("unroll")                                                  \
            for (int j = 0; j < 3; j++) {                                      \
                const short8 B = *(const short8*)&wsb[WB][offB[j][ks]];        \
                _Pragma("unroll")                                              \
                for (int i = 0; i < 2; i++)                                    \
                    acc[i][j] = __builtin_amdgcn_mfma_f32_16x16x32_bf16(       \
                        A[i][ks].s8, B, acc[i][j], 0, 0, 0);                   \
            }                                                                  \
    } while (0)

    // ---- main loop (iters 0..30): wait x(j)+W(j) only, x(j+1) stays in flight
    for (int k0 = 0; k0 < EMB_D - 64; k0 += 64) {
        const int it = k0 >> 6;
        asm volatile("s_waitcnt vmcnt(4)\n\ts_barrier" ::: "memory");
        // issue W(j+1) first (so it ages ahead of x(j+2)), then x(j+2)
#pragma unroll
        for (int p = 0; p < 3; p++)
            dma16(wSrc[p] + k0 + 64, &wsb[(it + 1) & 1][wOff[p]]);
        if (k0 + 128 < EMB_D) {
#pragma unroll
            for (int p = 0; p < 4; p++)
                dma16(xSrc[p] + k0 + 128, &xs[(it + 2) % 3][xOff[p]]);
        }
        QKV_COMPUTE(it % 3, it & 1);
    }
    // ---- final iteration (it = 31): drain everything
    asm volatile("s_waitcnt vmcnt(0)\n\ts_barrier" ::: "memory");
    QKV_COMPUTE(31 % 3, 31 & 1);
#undef QKV_COMPUTE

    const float qscale = 0.08838834764831845f * 1.4426950408889634f; // 1/sqrt(128)*log2(e)
#pragma unroll
    for (int i = 0; i < 2; i++) {
#pragma unroll
        for (int r = 0; r < 4; r++) {
            const int row = m0 + wm * 32 + i * 16 + lq * 4 + r;   // b*T + t
            const int t = row & (T_SEQ - 1);
            const int bb = row >> 11;
#pragma unroll
            for (int j = 0; j < 3; j++) {
                const int col = ng * 96 + wn * 48 + j * 16 + l15;
                const int mat = col >> 7, mcol = col & 127;
                const float v = acc[i][j][r];
                if (mat == 2) {
                    Vt[((size_t)bb * HD_D + mcol) * T_SEQ + t] = f2bf_rne(v);
                } else {
                    const int ip = mcol >> 1;
                    const float c = rcos[t * 64 + ip];
                    const float s2 = rsin[t * 64 + ip];
                    const float pv = __shfl_xor(v, 1);
                    float rv = (mcol & 1) ? (pv * s2 + v * c) : (v * c - pv * s2);
                    if (mat == 0) {
                        rv *= qscale;
                        Qb[(size_t)row * HD_D + mcol] = f2bf_rne(rv);
                    } else {
                        Kb[(size_t)row * HD_D + mcol] = f2bf_rne(rv);
                    }
                }
            }
        }
    }
}

// ---------------------------------------------------------------------------
// Kernel 2: flash attention, causal, STATIC-MAX softmax, SPLIT-K v2.
//   (R12 version, frozen: bounds (256,2), bf16 O_s, 4 blocks/CU)
// ---------------------------------------------------------------------------
__global__ __launch_bounds__(256, 2) void attn(
    const unsigned short* __restrict__ Qb, const unsigned short* __restrict__ Kb,
    const unsigned short* __restrict__ Vt, float* __restrict__ O0,
    unsigned short* __restrict__ O1, float* __restrict__ Lp)
{
    __shared__ __attribute__((aligned(16))) unsigned short O_s[4][16 * 128];   // 16 KB
    __shared__ __attribute__((aligned(16))) unsigned short P_s[4][2][16 * 40]; // 10 KB
    __shared__ float l_s[4][16];

    const int tid = threadIdx.x;
    const int lane = tid & 63, wave = tid >> 6;
    const int l15 = lane & 15, lq = lane >> 4;
    const int kf = lq * 8;

    const int L = blockIdx.x;
    const int g = L & 1;                         // k-group
    const int b = (L >> 1) & 3;
    const int q0 = (127 - (L >> 3)) * 16;        // heavy q-tiles first
    const int kend = q0 + 16;
    const float M2 = 16.0f;                      // static max (exp2 domain)

    const unsigned short* Qp = Qb + (size_t)(b * T_SEQ + q0) * HD_D;
    short8 aQ[4];
#pragma unroll
    for (int d = 0; d < 4; d++)
        aQ[d] = *(const short8*)&Qp[l15 * HD_D + d * 32 + kf];

    f32x4 acc[8];
#pragma unroll
    for (int d = 0; d < 8; d++) acc[d] = (f32x4){0.f, 0.f, 0.f, 0.f};
    float l_r[4] = {0.f, 0.f, 0.f, 0.f};

    const unsigned short* Kbase = Kb + (size_t)b * T_SEQ * HD_D;
    const unsigned short* Vbase = Vt + (size_t)b * HD_D * T_SEQ;
    unsigned short* PwA = &P_s[wave][0][0];
    unsigned short* PwB = &P_s[wave][1][0];

    for (int c = 2 * wave + g; c * 32 < kend; c += 16) {
        const int kA = c * 32;
        const int kB = (c + 8) * 32;
        const bool hB = kB < kend;

        const unsigned short* KpA = Kbase + (size_t)kA * HD_D;
        const unsigned short* KpB = Kbase + (size_t)kB * HD_D;
        short8 KA[8], KB_[8];
#pragma unroll
        for (int d = 0; d < 4; d++)
#pragma unroll
            for (int n = 0; n < 2; n++)
                KA[d * 2 + n] = *(const short8*)&KpA[(size_t)(n * 16 + l15) * HD_D + d * 32 + kf];
        if (hB) {
#pragma unroll
            for (int d = 0; d < 4; d++)
#pragma unroll
                for (int n = 0; n < 2; n++)
                    KB_[d * 2 + n] = *(const short8*)&KpB[(size_t)(n * 16 + l15) * HD_D + d * 32 + kf];
        }

        f32x4 sA0 = (f32x4){0.f, 0.f, 0.f, 0.f}, sA1 = sA0, sB0 = sA0, sB1 = sA0;
#pragma unroll
        for (int d = 0; d < 4; d++) {
            sA0 = __builtin_amdgcn_mfma_f32_16x16x32_bf16(aQ[d], KA[d * 2 + 0], sA0, 0, 0, 0);
            sA1 = __builtin_amdgcn_mfma_f32_16x16x32_bf16(aQ[d], KA[d * 2 + 1], sA1, 0, 0, 0);
        }
        if (hB) {
#pragma unroll
            for (int d = 0; d < 4; d++) {
                sB0 = __builtin_amdgcn_mfma_f32_16x16x32_bf16(aQ[d], KB_[d * 2 + 0], sB0, 0, 0, 0);
                sB1 = __builtin_amdgcn_mfma_f32_16x16x32_bf16(aQ[d], KB_[d * 2 + 1], sB1, 0, 0, 0);
            }
        }

        short8 VA[8];
#pragma unroll
        for (int d = 0; d < 8; d++)
            VA[d] = *(const short8*)&Vbase[(size_t)(d * 16 + l15) * T_SEQ + kA + kf];

#pragma unroll
        for (int r = 0; r < 4; r++) {
            const int q = q0 + lq * 4 + r;
            const float p0 = ((kA + l15)      <= q) ? EXP2F(sA0[r] - M2) : 0.f;
            const float p1 = ((kA + 16 + l15) <= q) ? EXP2F(sA1[r] - M2) : 0.f;
            l_r[r] += p0 + p1;
            const int prow = (lq * 4 + r) * 40;
            PwA[prow + l15]      = f2bf_fast(p0);
            PwA[prow + 16 + l15] = f2bf_fast(p1);
        }
        const short8 pA = *(const short8*)&PwA[l15 * 40 + kf];
#pragma unroll
        for (int d = 0; d < 8; d++)
            acc[d] = __builtin_amdgcn_mfma_f32_16x16x32_bf16(pA, VA[d], acc[d], 0, 0, 0);

        if (hB) {
            short8 VB[8];
#pragma unroll
            for (int d = 0; d < 8; d++)
                VB[d] = *(const short8*)&Vbase[(size_t)(d * 16 + l15) * T_SEQ + kB + kf];
#pragma unroll
            for (int r = 0; r < 4; r++) {
                const int q = q0 + lq * 4 + r;
                const float p0 = ((kB + l15)      <= q) ? EXP2F(sB0[r] - M2) : 0.f;
                const float p1 = ((kB + 16 + l15) <= q) ? EXP2F(sB1[r] - M2) : 0.f;
                l_r[r] += p0 + p1;
                const int prow = (lq * 4 + r) * 40;
                PwB[prow + l15]      = f2bf_fast(p0);
                PwB[prow + 16 + l15] = f2bf_fast(p1);
            }
            const short8 pB = *(const short8*)&PwB[l15 * 40 + kf];
#pragma unroll
            for (int d = 0; d < 8; d++)
                acc[d] = __builtin_amdgcn_mfma_f32_16x16x32_bf16(pB, VB[d], acc[d], 0, 0, 0);
        }
    }

#pragma unroll
    for (int r = 0; r < 4; r++) {
        float lr = l_r[r];
        lr += __shfl_xor(lr, 1);
        lr += __shfl_xor(lr, 2);
        lr += __shfl_xor(lr, 4);
        lr += __shfl_xor(lr, 8);
        if (l15 == 0) l_s[wave][lq * 4 + r] = lr;
#pragma unroll
        for (int d = 0; d < 8; d++)
            O_s[wave][(lq * 4 + r) * 128 + d * 16 + l15] = f2bf_fast(acc[d][r]);
    }
    __syncthreads();

    const int row = tid >> 4;
    const int dc = (tid & 15) * 8;
    const float lt = l_s[0][row] + l_s[1][row] + l_s[2][row] + l_s[3][row];
    float o[8];
#pragma unroll
    for (int k = 0; k < 8; k++) o[k] = 0.f;
#pragma unroll
    for (int w2 = 0; w2 < 4; w2++) {
        const ushort8v pv = *(const ushort8v*)&O_s[w2][row * 128 + dc];
#pragma unroll
        for (int k = 0; k < 8; k++) o[k] += bf2f(pv[k]);
    }
    const size_t grow = (size_t)(b * T_SEQ + q0 + row);
    if (g == 0) {
        float* op = O0 + grow * HD_D + dc;
#pragma unroll
        for (int k = 0; k < 8; k++) op[k] = o[k];
    } else {
        ushort8v h;
#pragma unroll
        for (int k = 0; k < 8; k++) h[k] = f2bf_fast(o[k]);
        *(ushort8v*)&O1[grow * HD_D + dc] = h;
    }
    if ((tid & 15) == 0) Lp[g * 8192 + grow] = lt;
}

// ---------------------------------------------------------------------------
// Kernel 3: combine the two k-group partials: out = (O0 + O1) / (l0 + l1)
// ---------------------------------------------------------------------------
__global__ __launch_bounds__(256) void attn_merge(
    float* __restrict__ out, const unsigned short* __restrict__ O1,
    const float* __restrict__ Lp)
{
    const int idx = blockIdx.x * 256 + threadIdx.x;   // f32x4 index (262144)
    const int row = idx >> 5;                          // 32 f32x4 per row
    f32x4 a = ((f32x4*)out)[idx];
    const ushort4v h = ((const ushort4v*)O1)[idx];
    f32x4 bv = { bf2f(h.x), bf2f(h.y), bf2f(h.z), bf2f(h.w) };
    const float inv = 1.0f / (Lp[row] + Lp[8192 + row]);
    ((f32x4*)out)[idx] = (a + bv) * inv;
}

// ---------------------------------------------------------------------------
extern "C" void kernel_launch(void* const* d_in, const int* in_sizes, int n_in,
                              void* d_out, int out_size, void* d_ws, size_t ws_size,
                              hipStream_t stream)
{
    (void)in_sizes; (void)n_in; (void)out_size; (void)ws_size;
    const float* x  = (const float*)d_in[0];
    const float* Wq = (const float*)d_in[1];
    const float* Wk = (const float*)d_in[2];
    const float* Wv = (const float*)d_in[3];
    const float* rc = (const float*)d_in[4];
    const float* rs = (const float*)d_in[5];
    // d_in[6] = additive causal mask: handled analytically, not read.
    float* out = (float*)d_out;

    char* ws = (char*)d_ws;
    unsigned short* Wt = (unsigned short*)(ws);                    // 1,572,864 B
    unsigned short* Qb = (unsigned short*)(ws + 1572864);          // 2,097,152 B
    unsigned short* Kb = (unsigned short*)(ws + 3670016);          // 2,097,152 B
    unsigned short* Vt = (unsigned short*)(ws + 5767168);          // 2,097,152 B
    unsigned short* O1 = (unsigned short*)(ws + 7864320);          // 2,097,152 B
    float*          Lp = (float*)(ws + 9961472);                   //    65,536 B

    prep_weights<<<dim3(32, 3), 256, 0, stream>>>(Wq, Wk, Wv, Wt);
    qkv_fused   <<<dim3(512),   256, 0, stream>>>(x, Wt, rc, rs, Qb, Kb, Vt);
    attn        <<<dim3(1024),  256, 0, stream>>>(Qb, Kb, Vt, out, O1, Lp);
    attn_merge  <<<dim3(1024),  256, 0, stream>>>(out, O1, Lp);
}